// Round 1
// baseline (503.617 us; speedup 1.0000x reference)
//
#include <hip/hip_runtime.h>

#define N0 6400
#define NC 256
#define WW 80

// ---------------- workspace layout (float offsets) ----------------
// A  (f0 normalized, row-major [n][c])  @ 0         (1,638,400)
// B  (f1 normalized, row-major [m][c])  @ 1,638,400 (1,638,400)
// inv0 @ 3,276,800   inv1 @ 3,283,200
// rowsum @ 3,289,600  colsum @ 3,296,000
// rowbest (u64 x 6400) @ float-off 3,302,400
// colbest (u64 x 6400) @ float-off 3,315,200
// total 3,328,000 floats = 13.3 MB

// ---------------- K1: inverse L2 norms over channel dim ----------------
__global__ __launch_bounds__(256) void knorm(const float* __restrict__ f0,
                                             const float* __restrict__ f1,
                                             float* __restrict__ inv0,
                                             float* __restrict__ inv1) {
    int t = blockIdx.x * 256 + threadIdx.x;          // 0..12799
    const float* src = (t < N0) ? f0 : f1;
    int n = (t < N0) ? t : (t - N0);
    float s = 0.f;
#pragma unroll 8
    for (int c = 0; c < NC; ++c) {
        float v = src[c * N0 + n];
        s += v * v;
    }
    float inv = 1.0f / fmaxf(sqrtf(s), 1e-12f);
    if (t < N0) inv0[n] = inv; else inv1[n] = inv;
}

// ---------------- K2: transpose (C,N)->(N,C) with normalization --------
__global__ __launch_bounds__(256) void ktrans(const float* __restrict__ src,
                                              const float* __restrict__ inv,
                                              float* __restrict__ dst) {
    __shared__ float tile[32][33];
    int n0 = blockIdx.x * 32, c0 = blockIdx.y * 32;
    int tx = threadIdx.x, ty = threadIdx.y;          // 32 x 8
#pragma unroll
    for (int u = 0; u < 4; ++u)
        tile[ty + u * 8][tx] = src[(c0 + ty + u * 8) * N0 + n0 + tx];
    __syncthreads();
#pragma unroll
    for (int u = 0; u < 4; ++u) {
        int n = n0 + ty + u * 8;
        dst[n * NC + c0 + tx] = tile[tx][ty + u * 8] * inv[n];
    }
}

// ---------------- K3: fp32 GEMM -> E = exp(S), plus row/col sums -------
#define BM 128
#define BN 128
#define BK 16
#define LDT 132   // BM + 4 keeps float4 alignment, breaks pow2 strides

__global__ __launch_bounds__(256) void kgemm(const float* __restrict__ A,
                                             const float* __restrict__ B,
                                             float* __restrict__ E,
                                             float* __restrict__ rowsum,
                                             float* __restrict__ colsum) {
    __shared__ float As[BK * LDT];
    __shared__ float Bs[BK * LDT];
    __shared__ float cs[BN];
    int tid = threadIdx.x;
    int tx = tid & 15, ty = tid >> 4;
    int i0 = blockIdx.y * BM, j0 = blockIdx.x * BN;

    if (tid < BN) cs[tid] = 0.f;   // covered by first barrier in k-loop

    float acc[8][8] = {};

    for (int k0 = 0; k0 < NC; k0 += BK) {
#pragma unroll
        for (int l = 0; l < 2; ++l) {
            int m = tid + l * 256;
            int row = m >> 2;
            int kk = (m & 3) * 4;
            float4 va = *(const float4*)&A[(i0 + row) * NC + k0 + kk];
            As[(kk + 0) * LDT + row] = va.x;
            As[(kk + 1) * LDT + row] = va.y;
            As[(kk + 2) * LDT + row] = va.z;
            As[(kk + 3) * LDT + row] = va.w;
            float4 vb = *(const float4*)&B[(j0 + row) * NC + k0 + kk];
            Bs[(kk + 0) * LDT + row] = vb.x;
            Bs[(kk + 1) * LDT + row] = vb.y;
            Bs[(kk + 2) * LDT + row] = vb.z;
            Bs[(kk + 3) * LDT + row] = vb.w;
        }
        __syncthreads();
#pragma unroll
        for (int k = 0; k < BK; ++k) {
            float4 a0 = *(const float4*)&As[k * LDT + ty * 8];
            float4 a1 = *(const float4*)&As[k * LDT + ty * 8 + 4];
            float4 b0 = *(const float4*)&Bs[k * LDT + tx * 8];
            float4 b1 = *(const float4*)&Bs[k * LDT + tx * 8 + 4];
            float a[8] = {a0.x, a0.y, a0.z, a0.w, a1.x, a1.y, a1.z, a1.w};
            float b[8] = {b0.x, b0.y, b0.z, b0.w, b1.x, b1.y, b1.z, b1.w};
#pragma unroll
            for (int u = 0; u < 8; ++u)
#pragma unroll
                for (int v = 0; v < 8; ++v)
                    acc[u][v] += a[u] * b[v];
        }
        __syncthreads();
    }

    // epilogue: E = exp(S), S = 10*cos; write + partial sums
    float rsum[8], csum[8];
#pragma unroll
    for (int u = 0; u < 8; ++u) rsum[u] = 0.f;
#pragma unroll
    for (int v = 0; v < 8; ++v) csum[v] = 0.f;

#pragma unroll
    for (int u = 0; u < 8; ++u) {
        float e[8];
#pragma unroll
        for (int v = 0; v < 8; ++v) {
            e[v] = __expf(10.0f * acc[u][v]);
            rsum[u] += e[v];
            csum[v] += e[v];
        }
        int row = i0 + ty * 8 + u;
        float4 e0 = make_float4(e[0], e[1], e[2], e[3]);
        float4 e1 = make_float4(e[4], e[5], e[6], e[7]);
        *(float4*)&E[row * N0 + j0 + tx * 8]     = e0;
        *(float4*)&E[row * N0 + j0 + tx * 8 + 4] = e1;
    }

    // rowsum: reduce over tx (lane bits 0..3)
#pragma unroll
    for (int s = 1; s < 16; s <<= 1)
#pragma unroll
        for (int u = 0; u < 8; ++u) rsum[u] += __shfl_xor(rsum[u], s);
    if ((tid & 15) == 0)
#pragma unroll
        for (int u = 0; u < 8; ++u)
            atomicAdd(&rowsum[i0 + ty * 8 + u], rsum[u]);

    // colsum: reduce over ty-within-wave (lane bits 4..5), then LDS, then global
#pragma unroll
    for (int s = 16; s < 64; s <<= 1)
#pragma unroll
        for (int v = 0; v < 8; ++v) csum[v] += __shfl_xor(csum[v], s);
    if ((tid & 63) < 16)
#pragma unroll
        for (int v = 0; v < 8; ++v)
            atomicAdd(&cs[tx * 8 + v], csum[v]);
    __syncthreads();
    if (tid < BN) atomicAdd(&colsum[j0 + tid], cs[tid]);
}

// ---------------- K4: E -> P in place, track row/col argmax ------------
__device__ __forceinline__ unsigned long long packvi(float v, int i) {
    return ((unsigned long long)__float_as_uint(v) << 32) | (unsigned int)i;
}

__global__ __launch_bounds__(256) void kpass(const float* __restrict__ rowsum,
                                             const float* __restrict__ colsum,
                                             float* __restrict__ P,
                                             unsigned long long* __restrict__ rowbest,
                                             unsigned long long* __restrict__ colbest) {
    int lane = threadIdx.x & 63;
    int wave = threadIdx.x >> 6;
    int j0 = blockIdx.x * 256;   // 25 col blocks
    int i0 = blockIdx.y * 160;   // 40 row blocks
    int j = j0 + lane * 4;

    float4 c4 = *(const float4*)&colsum[j];
    float invc0 = 1.0f / c4.x, invc1 = 1.0f / c4.y,
          invc2 = 1.0f / c4.z, invc3 = 1.0f / c4.w;

    float cbv[4] = {0.f, 0.f, 0.f, 0.f};
    int   cbi[4] = {0, 0, 0, 0};

    for (int r = 0; r < 40; ++r) {
        int i = i0 + wave + r * 4;               // each wave owns disjoint rows
        float invr = 1.0f / rowsum[i];
        float4 e4 = *(const float4*)&P[i * N0 + j];
        float p0 = e4.x * e4.x * invr * invc0;
        float p1 = e4.y * e4.y * invr * invc1;
        float p2 = e4.z * e4.z * invr * invc2;
        float p3 = e4.w * e4.w * invr * invc3;
        *(float4*)&P[i * N0 + j] = make_float4(p0, p1, p2, p3);

        // row best across this wave's 256 columns
        float bv = p0; int bj = j;
        if (p1 > bv) { bv = p1; bj = j + 1; }
        if (p2 > bv) { bv = p2; bj = j + 2; }
        if (p3 > bv) { bv = p3; bj = j + 3; }
#pragma unroll
        for (int s = 1; s < 64; s <<= 1) {
            float ov = __shfl_xor(bv, s);
            int   oj = __shfl_xor(bj, s);
            if (ov > bv) { bv = ov; bj = oj; }
        }
        if (lane == 0) atomicMax(&rowbest[i], packvi(bv, bj));

        // column best (per-lane registers)
        if (p0 > cbv[0]) { cbv[0] = p0; cbi[0] = i; }
        if (p1 > cbv[1]) { cbv[1] = p1; cbi[1] = i; }
        if (p2 > cbv[2]) { cbv[2] = p2; cbi[2] = i; }
        if (p3 > cbv[3]) { cbv[3] = p3; cbi[3] = i; }
    }
#pragma unroll
    for (int v = 0; v < 4; ++v)
        atomicMax(&colbest[j + v], packvi(cbv[v], cbi[v]));
}

// ---------------- K5: mutual-NN matching outputs -----------------------
__global__ __launch_bounds__(256) void kmatch(const unsigned long long* __restrict__ rowbest,
                                              const unsigned long long* __restrict__ colbest,
                                              float* __restrict__ out) {
    int i = blockIdx.x * 256 + threadIdx.x;      // 0..6399
    unsigned long long rb = rowbest[i];
    float conf = __uint_as_float((unsigned int)(rb >> 32));
    int jj = (int)(rb & 0xffffffffu);
    unsigned long long cb = colbest[jj];
    int i2 = (int)(cb & 0xffffffffu);
    bool valid = (i2 == i) && (conf > 0.2f);
    float vf = valid ? 1.0f : 0.0f;

    float* mk0   = out + 40960000;
    float* mk1   = out + 40972800;
    float* mconf = out + 40985600;
    float* vout  = out + 40992000;
    mk0[i * 2 + 0] = vf * (float)(i % WW);
    mk0[i * 2 + 1] = vf * (float)(i / WW);
    mk1[i * 2 + 0] = vf * (float)(jj % WW);
    mk1[i * 2 + 1] = vf * (float)(jj / WW);
    mconf[i] = valid ? conf : 0.0f;
    vout[i]  = vf;
}

extern "C" void kernel_launch(void* const* d_in, const int* in_sizes, int n_in,
                              void* d_out, int out_size, void* d_ws, size_t ws_size,
                              hipStream_t stream) {
    const float* f0 = (const float*)d_in[0];
    const float* f1 = (const float*)d_in[1];
    float* out = (float*)d_out;
    float* ws = (float*)d_ws;

    float* A    = ws;
    float* B    = ws + 1638400;
    float* inv0 = ws + 3276800;
    float* inv1 = ws + 3283200;
    float* rowsum = ws + 3289600;
    float* colsum = ws + 3296000;
    unsigned long long* rowbest = (unsigned long long*)(ws + 3302400);
    unsigned long long* colbest = (unsigned long long*)(ws + 3315200);

    // zero sums + best arrays (contiguous 153600 bytes)
    hipMemsetAsync(ws + 3289600, 0, 38400 * sizeof(float), stream);

    knorm<<<50, 256, 0, stream>>>(f0, f1, inv0, inv1);
    dim3 tb(32, 8);
    ktrans<<<dim3(200, 8), tb, 0, stream>>>(f0, inv0, A);
    ktrans<<<dim3(200, 8), tb, 0, stream>>>(f1, inv1, B);
    kgemm<<<dim3(50, 50), 256, 0, stream>>>(A, B, out, rowsum, colsum);
    kpass<<<dim3(25, 40), 256, 0, stream>>>(rowsum, colsum, out, rowbest, colbest);
    kmatch<<<25, 256, 0, stream>>>(rowbest, colbest, out);
}

// Round 2
// 326.203 us; speedup vs baseline: 1.5439x; 1.5439x over previous
//
#include <hip/hip_runtime.h>

#define N0 6400
#define NC 256
#define WW 80

using short8  = __attribute__((ext_vector_type(8))) short;
using floatx4 = __attribute__((ext_vector_type(4))) float;
#define GLOBAL_AS __attribute__((address_space(1)))
#define LDS_AS    __attribute__((address_space(3)))

// round-to-nearest-even float -> bf16 bits
__device__ __forceinline__ unsigned short f2bf(float x) {
    unsigned u = __float_as_uint(x);
    u += 0x7fffu + ((u >> 16) & 1u);
    return (unsigned short)(u >> 16);
}
__device__ __forceinline__ float bf2f(unsigned short h) {
    return __uint_as_float(((unsigned)h) << 16);
}

// ---------------- K1: inverse L2 norms over channel dim ----------------
__global__ __launch_bounds__(256) void knorm(const float* __restrict__ f0,
                                             const float* __restrict__ f1,
                                             float* __restrict__ inv0,
                                             float* __restrict__ inv1) {
    int t = blockIdx.x * 256 + threadIdx.x;          // 0..12799
    const float* src = (t < N0) ? f0 : f1;
    int n = (t < N0) ? t : (t - N0);
    float s = 0.f;
#pragma unroll 8
    for (int c = 0; c < NC; ++c) {
        float v = src[c * N0 + n];
        s += v * v;
    }
    float inv = 1.0f / fmaxf(sqrtf(s), 1e-12f);
    if (t < N0) inv0[n] = inv; else inv1[n] = inv;
}

// -------- K2: transpose (C,N)->(N,512) bf16 split hi|lo, normalized ----
__global__ __launch_bounds__(256) void ktrans(const float* __restrict__ src,
                                              const float* __restrict__ inv,
                                              unsigned short* __restrict__ dst) {
    __shared__ float tile[32][33];
    int t = threadIdx.x;
    int n0 = blockIdx.x * 32, c0 = blockIdx.y * 32;
    int tx = t & 31, ty = t >> 5;                    // 32 x 8
#pragma unroll
    for (int u = 0; u < 4; ++u)
        tile[ty + u * 8][tx] = src[(c0 + ty + u * 8) * N0 + n0 + tx];
    __syncthreads();
    int row = t >> 3;            // 0..31 (local n)
    int cg  = (t & 7) * 4;       // 0..28 (local c, groups of 4)
    int n = n0 + row;
    float iv = inv[n];
    unsigned short h[4], l[4];
#pragma unroll
    for (int u = 0; u < 4; ++u) {
        float v = tile[cg + u][row] * iv;
        h[u] = f2bf(v);
        l[u] = f2bf(v - bf2f(h[u]));
    }
    ushort4 hv; hv.x = h[0]; hv.y = h[1]; hv.z = h[2]; hv.w = h[3];
    ushort4 lv; lv.x = l[0]; lv.y = l[1]; lv.z = l[2]; lv.w = l[3];
    *(ushort4*)&dst[n * 512 + c0 + cg]       = hv;   // hi half: cols 0..255
    *(ushort4*)&dst[n * 512 + 256 + c0 + cg] = lv;   // lo half: cols 256..511
}

// ---------------- K3: split-bf16 MFMA GEMM -> E = exp(S) + sums --------
// LDS: 4 tiles (Ahi|Alo|Bhi|Blo), each 128 rows x 32 k bf16, stored as
// 16B chunks at slot = row*4 + (kc ^ ((row>>1)&3))   (fetch-side swizzle)
__global__ __launch_bounds__(256) void kgemm(const unsigned short* __restrict__ A2,
                                             const unsigned short* __restrict__ B2,
                                             float* __restrict__ E,
                                             float* __restrict__ rowsum,
                                             float* __restrict__ colsum) {
    __shared__ __align__(16) unsigned short lds[4 * 4096];
    __shared__ float rs[128], cs[128];
    int tid = threadIdx.x;
    int lane = tid & 63, wave = tid >> 6;
    int wm = wave & 1, wn = wave >> 1;
    int i0 = blockIdx.y * 128, j0 = blockIdx.x * 128;

    if (tid < 128) rs[tid] = 0.f; else cs[tid - 128] = 0.f;

    // staging map: thread handles LDS slots tid and tid+256 of each tile
    int r1 = tid >> 2;
    int kc1 = (tid & 3) ^ ((r1 >> 1) & 3);
    int r2 = r1 + 64;
    int kc2 = (tid & 3) ^ ((r2 >> 1) & 3);

    floatx4 acc[4][4] = {};

    for (int k0 = 0; k0 < NC; k0 += 32) {
        __syncthreads();
        const unsigned short* ga1 = A2 + (i0 + r1) * 512 + k0 + kc1 * 8;
        const unsigned short* ga2 = A2 + (i0 + r2) * 512 + k0 + kc2 * 8;
        const unsigned short* gb1 = B2 + (j0 + r1) * 512 + k0 + kc1 * 8;
        const unsigned short* gb2 = B2 + (j0 + r2) * 512 + k0 + kc2 * 8;
        // Ahi tile @0, Alo @4096, Bhi @8192, Blo @12288 (ushort units)
        __builtin_amdgcn_global_load_lds((const GLOBAL_AS unsigned int*)ga1,
                                         (LDS_AS unsigned int*)&lds[tid * 8], 16, 0, 0);
        __builtin_amdgcn_global_load_lds((const GLOBAL_AS unsigned int*)ga2,
                                         (LDS_AS unsigned int*)&lds[2048 + tid * 8], 16, 0, 0);
        __builtin_amdgcn_global_load_lds((const GLOBAL_AS unsigned int*)(ga1 + 256),
                                         (LDS_AS unsigned int*)&lds[4096 + tid * 8], 16, 0, 0);
        __builtin_amdgcn_global_load_lds((const GLOBAL_AS unsigned int*)(ga2 + 256),
                                         (LDS_AS unsigned int*)&lds[4096 + 2048 + tid * 8], 16, 0, 0);
        __builtin_amdgcn_global_load_lds((const GLOBAL_AS unsigned int*)gb1,
                                         (LDS_AS unsigned int*)&lds[8192 + tid * 8], 16, 0, 0);
        __builtin_amdgcn_global_load_lds((const GLOBAL_AS unsigned int*)gb2,
                                         (LDS_AS unsigned int*)&lds[8192 + 2048 + tid * 8], 16, 0, 0);
        __builtin_amdgcn_global_load_lds((const GLOBAL_AS unsigned int*)(gb1 + 256),
                                         (LDS_AS unsigned int*)&lds[12288 + tid * 8], 16, 0, 0);
        __builtin_amdgcn_global_load_lds((const GLOBAL_AS unsigned int*)(gb2 + 256),
                                         (LDS_AS unsigned int*)&lds[12288 + 2048 + tid * 8], 16, 0, 0);
        __syncthreads();   // drains vmcnt(0) before barrier

        short8 ah[4], al[4], bh[4], bl[4];
        int q = lane >> 4;
#pragma unroll
        for (int mt = 0; mt < 4; ++mt) {
            int rowa = wm * 64 + mt * 16 + (lane & 15);
            int sa = rowa * 4 + (q ^ ((rowa >> 1) & 3));
            ah[mt] = *(const short8*)&lds[sa * 8];
            al[mt] = *(const short8*)&lds[4096 + sa * 8];
            int rowb = wn * 64 + mt * 16 + (lane & 15);
            int sb = rowb * 4 + (q ^ ((rowb >> 1) & 3));
            bh[mt] = *(const short8*)&lds[8192 + sb * 8];
            bl[mt] = *(const short8*)&lds[12288 + sb * 8];
        }
#pragma unroll
        for (int mt = 0; mt < 4; ++mt)
#pragma unroll
            for (int nt = 0; nt < 4; ++nt) {
                acc[mt][nt] = __builtin_amdgcn_mfma_f32_16x16x32_bf16(ah[mt], bh[nt], acc[mt][nt], 0, 0, 0);
                acc[mt][nt] = __builtin_amdgcn_mfma_f32_16x16x32_bf16(ah[mt], bl[nt], acc[mt][nt], 0, 0, 0);
                acc[mt][nt] = __builtin_amdgcn_mfma_f32_16x16x32_bf16(al[mt], bh[nt], acc[mt][nt], 0, 0, 0);
            }
    }

    // epilogue: e = exp(10*acc); write E; row/col sums via LDS then global
    int quad = lane >> 4;
    int colbase = j0 + wn * 64 + (lane & 15);
    float csum[4] = {0.f, 0.f, 0.f, 0.f};
#pragma unroll
    for (int mt = 0; mt < 4; ++mt) {
#pragma unroll
        for (int r = 0; r < 4; ++r) {
            int row = i0 + wm * 64 + mt * 16 + quad * 4 + r;
            float rsv = 0.f;
#pragma unroll
            for (int nt = 0; nt < 4; ++nt) {
                float e = __expf(10.0f * acc[mt][nt][r]);
                E[row * N0 + colbase + nt * 16] = e;
                rsv += e;
                csum[nt] += e;
            }
            rsv += __shfl_xor(rsv, 1);
            rsv += __shfl_xor(rsv, 2);
            rsv += __shfl_xor(rsv, 4);
            rsv += __shfl_xor(rsv, 8);
            if ((lane & 15) == 0) atomicAdd(&rs[row - i0], rsv);
        }
    }
#pragma unroll
    for (int nt = 0; nt < 4; ++nt) {
        csum[nt] += __shfl_xor(csum[nt], 16);
        csum[nt] += __shfl_xor(csum[nt], 32);
    }
    if (lane < 16)
#pragma unroll
        for (int nt = 0; nt < 4; ++nt)
            atomicAdd(&cs[wn * 64 + nt * 16 + lane], csum[nt]);
    __syncthreads();
    if (tid < 128) atomicAdd(&rowsum[i0 + tid], rs[tid]);
    else           atomicAdd(&colsum[j0 + tid - 128], cs[tid - 128]);
}

// ---------------- K4: E -> P in place, track row/col argmax ------------
__device__ __forceinline__ unsigned long long packvi(float v, int i) {
    return ((unsigned long long)__float_as_uint(v) << 32) | (unsigned int)i;
}

__global__ __launch_bounds__(256) void kpass(const float* __restrict__ rowsum,
                                             const float* __restrict__ colsum,
                                             float* __restrict__ P,
                                             unsigned long long* __restrict__ rowbest,
                                             unsigned long long* __restrict__ colbest) {
    int lane = threadIdx.x & 63;
    int wave = threadIdx.x >> 6;
    int j0 = blockIdx.x * 256;   // 25 col blocks
    int i0 = blockIdx.y * 160;   // 40 row blocks
    int j = j0 + lane * 4;

    float4 c4 = *(const float4*)&colsum[j];
    float invc0 = 1.0f / c4.x, invc1 = 1.0f / c4.y,
          invc2 = 1.0f / c4.z, invc3 = 1.0f / c4.w;

    float cbv[4] = {0.f, 0.f, 0.f, 0.f};
    int   cbi[4] = {0, 0, 0, 0};

    for (int r = 0; r < 40; ++r) {
        int i = i0 + wave + r * 4;               // each wave owns disjoint rows
        float invr = 1.0f / rowsum[i];
        float4 e4 = *(const float4*)&P[i * N0 + j];
        float p0 = e4.x * e4.x * invr * invc0;
        float p1 = e4.y * e4.y * invr * invc1;
        float p2 = e4.z * e4.z * invr * invc2;
        float p3 = e4.w * e4.w * invr * invc3;
        *(float4*)&P[i * N0 + j] = make_float4(p0, p1, p2, p3);

        float bv = p0; int bj = j;
        if (p1 > bv) { bv = p1; bj = j + 1; }
        if (p2 > bv) { bv = p2; bj = j + 2; }
        if (p3 > bv) { bv = p3; bj = j + 3; }
#pragma unroll
        for (int s = 1; s < 64; s <<= 1) {
            float ov = __shfl_xor(bv, s);
            int   oj = __shfl_xor(bj, s);
            if (ov > bv) { bv = ov; bj = oj; }
        }
        if (lane == 0) atomicMax(&rowbest[i], packvi(bv, bj));

        if (p0 > cbv[0]) { cbv[0] = p0; cbi[0] = i; }
        if (p1 > cbv[1]) { cbv[1] = p1; cbi[1] = i; }
        if (p2 > cbv[2]) { cbv[2] = p2; cbi[2] = i; }
        if (p3 > cbv[3]) { cbv[3] = p3; cbi[3] = i; }
    }
#pragma unroll
    for (int v = 0; v < 4; ++v)
        atomicMax(&colbest[j + v], packvi(cbv[v], cbi[v]));
}

// ---------------- K5: mutual-NN matching outputs -----------------------
__global__ __launch_bounds__(256) void kmatch(const unsigned long long* __restrict__ rowbest,
                                              const unsigned long long* __restrict__ colbest,
                                              float* __restrict__ out) {
    int i = blockIdx.x * 256 + threadIdx.x;      // 0..6399
    unsigned long long rb = rowbest[i];
    float conf = __uint_as_float((unsigned int)(rb >> 32));
    int jj = (int)(rb & 0xffffffffu);
    unsigned long long cb = colbest[jj];
    int i2 = (int)(cb & 0xffffffffu);
    bool valid = (i2 == i) && (conf > 0.2f);
    float vf = valid ? 1.0f : 0.0f;

    float* mk0   = out + 40960000;
    float* mk1   = out + 40972800;
    float* mconf = out + 40985600;
    float* vout  = out + 40992000;
    mk0[i * 2 + 0] = vf * (float)(i % WW);
    mk0[i * 2 + 1] = vf * (float)(i / WW);
    mk1[i * 2 + 0] = vf * (float)(jj % WW);
    mk1[i * 2 + 1] = vf * (float)(jj / WW);
    mconf[i] = valid ? conf : 0.0f;
    vout[i]  = vf;
}

extern "C" void kernel_launch(void* const* d_in, const int* in_sizes, int n_in,
                              void* d_out, int out_size, void* d_ws, size_t ws_size,
                              hipStream_t stream) {
    const float* f0 = (const float*)d_in[0];
    const float* f1 = (const float*)d_in[1];
    float* out = (float*)d_out;

    unsigned short* A2 = (unsigned short*)d_ws;          // 6400x512 bf16 (hi|lo)
    unsigned short* B2 = A2 + 6400 * 512;
    float* inv0   = (float*)(B2 + 6400 * 512);
    float* inv1   = inv0 + 6400;
    float* rowsum = inv1 + 6400;
    float* colsum = rowsum + 6400;
    unsigned long long* rowbest = (unsigned long long*)(colsum + 6400);
    unsigned long long* colbest = rowbest + 6400;

    // zero rowsum/colsum/rowbest/colbest (contiguous 153,600 B)
    hipMemsetAsync(rowsum, 0, 153600, stream);

    knorm<<<50, 256, 0, stream>>>(f0, f1, inv0, inv1);
    ktrans<<<dim3(200, 8), 256, 0, stream>>>(f0, inv0, A2);
    ktrans<<<dim3(200, 8), 256, 0, stream>>>(f1, inv1, B2);
    kgemm<<<dim3(50, 50), 256, 0, stream>>>(A2, B2, out, rowsum, colsum);
    kpass<<<dim3(25, 40), 256, 0, stream>>>(rowsum, colsum, out, rowbest, colbest);
    kmatch<<<25, 256, 0, stream>>>(rowbest, colbest, out);
}

// Round 3
// 278.897 us; speedup vs baseline: 1.8057x; 1.1696x over previous
//
#include <hip/hip_runtime.h>

#define N0 6400
#define NC 256
#define WW 80

using half8   = __attribute__((ext_vector_type(8))) _Float16;
using floatx4 = __attribute__((ext_vector_type(4))) float;
#define GLOBAL_AS __attribute__((address_space(1)))
#define LDS_AS    __attribute__((address_space(3)))

__device__ __forceinline__ unsigned long long packvi(float v, int i) {
    return ((unsigned long long)__float_as_uint(v) << 32) | (unsigned int)i;
}

// ---------------- K1: inverse L2 norms over channel dim ----------------
__global__ __launch_bounds__(256) void knorm(const float* __restrict__ f0,
                                             const float* __restrict__ f1,
                                             float* __restrict__ inv0,
                                             float* __restrict__ inv1) {
    int t = blockIdx.x * 256 + threadIdx.x;          // 0..12799
    const float* src = (t < N0) ? f0 : f1;
    int n = (t < N0) ? t : (t - N0);
    float s = 0.f;
#pragma unroll 8
    for (int c = 0; c < NC; ++c) {
        float v = src[c * N0 + n];
        s += v * v;
    }
    float inv = 1.0f / fmaxf(sqrtf(s), 1e-12f);
    if (t < N0) inv0[n] = inv; else inv1[n] = inv;
}

// -------- K2: transpose (C,N)->(N,256) fp16, normalized ----------------
__global__ __launch_bounds__(256) void ktrans(const float* __restrict__ src,
                                              const float* __restrict__ inv,
                                              _Float16* __restrict__ dst) {
    __shared__ float tile[32][33];
    int t = threadIdx.x;
    int n0 = blockIdx.x * 32, c0 = blockIdx.y * 32;
    int tx = t & 31, ty = t >> 5;                    // 32 x 8
#pragma unroll
    for (int u = 0; u < 4; ++u)
        tile[ty + u * 8][tx] = src[(c0 + ty + u * 8) * N0 + n0 + tx];
    __syncthreads();
    int row = t >> 3;            // 0..31 (local n)
    int cg  = (t & 7) * 4;       // 0..28 (local c, groups of 4)
    int n = n0 + row;
    float iv = inv[n];
    union { ushort4 u4; _Float16 h[4]; } pk;
#pragma unroll
    for (int u = 0; u < 4; ++u)
        pk.h[u] = (_Float16)(tile[cg + u][row] * iv);
    *(ushort4*)&dst[n * NC + c0 + cg] = pk.u4;
}

// ---------------- shared GEMM core: 128x128 tile, fp16, K=256 ----------
// LDS tiles: 128 rows x 64 k fp16, row = 8 chunks of 16B, chunk XOR-swizzled
// by (row&7) on the FETCH side (keeps lane-linear global_load_lds legal).
__device__ __forceinline__ void gemm_core(const _Float16* __restrict__ A2,
                                          const _Float16* __restrict__ B2,
                                          unsigned short* ldsA, unsigned short* ldsB,
                                          int i0, int j0, int tid, int lane,
                                          int wm, int wn, floatx4 acc[4][4]) {
    int rl = tid >> 3;                               // 0..31
    int cg = ((tid & 7) ^ (rl & 7)) * 8;             // swizzled col (halves)
    int q  = lane >> 4;

    for (int k0 = 0; k0 < NC; k0 += 64) {
        __syncthreads();
#pragma unroll
        for (int g = 0; g < 4; ++g) {
            const _Float16* ga = A2 + (i0 + g * 32 + rl) * NC + k0 + cg;
            const _Float16* gb = B2 + (j0 + g * 32 + rl) * NC + k0 + cg;
            __builtin_amdgcn_global_load_lds((const GLOBAL_AS unsigned int*)ga,
                (LDS_AS unsigned int*)&ldsA[g * 2048 + tid * 8], 16, 0, 0);
            __builtin_amdgcn_global_load_lds((const GLOBAL_AS unsigned int*)gb,
                (LDS_AS unsigned int*)&ldsB[g * 2048 + tid * 8], 16, 0, 0);
        }
        __syncthreads();
#pragma unroll
        for (int s = 0; s < 2; ++s) {
            half8 af[4], bf[4];
#pragma unroll
            for (int mt = 0; mt < 4; ++mt) {
                int ra = wm * 64 + mt * 16 + (lane & 15);
                int ca = ((s * 4 + q) ^ (ra & 7)) * 8;
                af[mt] = *(const half8*)&ldsA[ra * 64 + ca];
                int rb = wn * 64 + mt * 16 + (lane & 15);
                int cb = ((s * 4 + q) ^ (rb & 7)) * 8;
                bf[mt] = *(const half8*)&ldsB[rb * 64 + cb];
            }
#pragma unroll
            for (int mt = 0; mt < 4; ++mt)
#pragma unroll
                for (int nt = 0; nt < 4; ++nt)
                    acc[mt][nt] = __builtin_amdgcn_mfma_f32_16x16x32_f16(
                        af[mt], bf[nt], acc[mt][nt], 0, 0, 0);
        }
    }
}

// ---------------- K3a: GEMM pass 1 — row/col sums of exp(S) only -------
__global__ __launch_bounds__(256) void kgemm1(const _Float16* __restrict__ A2,
                                              const _Float16* __restrict__ B2,
                                              float* __restrict__ rowsum,
                                              float* __restrict__ colsum) {
    __shared__ __align__(16) unsigned short ldsA[8192], ldsB[8192];
    __shared__ float rs[128], cs[128];
    int tid = threadIdx.x, lane = tid & 63, wave = tid >> 6;
    int wm = wave & 1, wn = wave >> 1;
    int i0 = blockIdx.y * 128, j0 = blockIdx.x * 128;
    if (tid < 128) rs[tid] = 0.f; else cs[tid - 128] = 0.f;  // covered by 1st barrier

    floatx4 acc[4][4] = {};
    gemm_core(A2, B2, ldsA, ldsB, i0, j0, tid, lane, wm, wn, acc);

    int quad = lane >> 4;
    float csum[4] = {0.f, 0.f, 0.f, 0.f};
#pragma unroll
    for (int mt = 0; mt < 4; ++mt)
#pragma unroll
        for (int r = 0; r < 4; ++r) {
            float rsv = 0.f;
#pragma unroll
            for (int nt = 0; nt < 4; ++nt) {
                float e = __expf(10.0f * acc[mt][nt][r]);
                rsv += e; csum[nt] += e;
            }
            rsv += __shfl_xor(rsv, 1);
            rsv += __shfl_xor(rsv, 2);
            rsv += __shfl_xor(rsv, 4);
            rsv += __shfl_xor(rsv, 8);
            if ((lane & 15) == 0) atomicAdd(&rs[wm * 64 + mt * 16 + quad * 4 + r], rsv);
        }
#pragma unroll
    for (int nt = 0; nt < 4; ++nt) {
        csum[nt] += __shfl_xor(csum[nt], 16);
        csum[nt] += __shfl_xor(csum[nt], 32);
    }
    if (lane < 16)
#pragma unroll
        for (int nt = 0; nt < 4; ++nt)
            atomicAdd(&cs[wn * 64 + nt * 16 + lane], csum[nt]);
    __syncthreads();
    if (tid < 128) atomicAdd(&rowsum[i0 + tid], rs[tid]);
    else           atomicAdd(&colsum[j0 + tid - 128], cs[tid - 128]);
}

// ---------------- K3b: reciprocal of rowsum|colsum (12800 floats) ------
__global__ __launch_bounds__(256) void kinv(float* __restrict__ sums) {
    int t = blockIdx.x * 256 + threadIdx.x;
    sums[t] = 1.0f / sums[t];
}

// ---------------- K4: GEMM pass 2 — P writes + fused argmax ------------
__global__ __launch_bounds__(256) void kgemm2(const _Float16* __restrict__ A2,
                                              const _Float16* __restrict__ B2,
                                              const float* __restrict__ invrow,
                                              const float* __restrict__ invcol,
                                              float* __restrict__ P,
                                              unsigned long long* __restrict__ rowbest,
                                              unsigned long long* __restrict__ colbest) {
    __shared__ __align__(16) unsigned short ldsA[8192], ldsB[8192];
    __shared__ unsigned long long rbst[128], cbst[128];
    int tid = threadIdx.x, lane = tid & 63, wave = tid >> 6;
    int wm = wave & 1, wn = wave >> 1;
    int i0 = blockIdx.y * 128, j0 = blockIdx.x * 128;
    if (tid < 128) rbst[tid] = 0ull; else cbst[tid - 128] = 0ull;

    floatx4 acc[4][4] = {};
    gemm_core(A2, B2, ldsA, ldsB, i0, j0, tid, lane, wm, wn, acc);

    int quad = lane >> 4;
    int cb0 = j0 + wn * 64 + (lane & 15);
    float invc[4];
#pragma unroll
    for (int nt = 0; nt < 4; ++nt) invc[nt] = invcol[cb0 + nt * 16];

    unsigned long long colb[4] = {0ull, 0ull, 0ull, 0ull};
#pragma unroll
    for (int mt = 0; mt < 4; ++mt) {
        int rb0 = i0 + wm * 64 + mt * 16 + quad * 4;     // 4-aligned
        float4 ir4 = *(const float4*)&invrow[rb0];
        float ir[4] = {ir4.x, ir4.y, ir4.z, ir4.w};
#pragma unroll
        for (int r = 0; r < 4; ++r) {
            int row = rb0 + r;
            unsigned long long rbv = 0ull;
#pragma unroll
            for (int nt = 0; nt < 4; ++nt) {
                float pv = __expf(20.0f * acc[mt][nt][r]) * ir[r] * invc[nt];
                P[row * N0 + cb0 + nt * 16] = pv;
                unsigned long long pr = packvi(pv, cb0 + nt * 16);
                if (pr > rbv) rbv = pr;
                unsigned long long pc = packvi(pv, row);
                if (pc > colb[nt]) colb[nt] = pc;
            }
#pragma unroll
            for (int s = 1; s < 16; s <<= 1) {
                unsigned long long o = __shfl_xor(rbv, s);
                if (o > rbv) rbv = o;
            }
            if ((lane & 15) == 0) atomicMax(&rbst[row - i0], rbv);
        }
    }
#pragma unroll
    for (int nt = 0; nt < 4; ++nt) {
        unsigned long long o = __shfl_xor(colb[nt], 16);
        if (o > colb[nt]) colb[nt] = o;
        o = __shfl_xor(colb[nt], 32);
        if (o > colb[nt]) colb[nt] = o;
    }
    if (lane < 16)
#pragma unroll
        for (int nt = 0; nt < 4; ++nt)
            atomicMax(&cbst[wn * 64 + nt * 16 + lane], colb[nt]);
    __syncthreads();
    if (tid < 128) atomicMax(&rowbest[i0 + tid], rbst[tid]);
    else           atomicMax(&colbest[j0 + tid - 128], cbst[tid - 128]);
}

// ---------------- K5: mutual-NN matching outputs -----------------------
__global__ __launch_bounds__(256) void kmatch(const unsigned long long* __restrict__ rowbest,
                                              const unsigned long long* __restrict__ colbest,
                                              float* __restrict__ out) {
    int i = blockIdx.x * 256 + threadIdx.x;      // 0..6399
    unsigned long long rb = rowbest[i];
    float conf = __uint_as_float((unsigned int)(rb >> 32));
    int jj = (int)(rb & 0xffffffffu);
    unsigned long long cb = colbest[jj];
    int i2 = (int)(cb & 0xffffffffu);
    bool valid = (i2 == i) && (conf > 0.2f);
    float vf = valid ? 1.0f : 0.0f;

    float* mk0   = out + 40960000;
    float* mk1   = out + 40972800;
    float* mconf = out + 40985600;
    float* vout  = out + 40992000;
    mk0[i * 2 + 0] = vf * (float)(i % WW);
    mk0[i * 2 + 1] = vf * (float)(i / WW);
    mk1[i * 2 + 0] = vf * (float)(jj % WW);
    mk1[i * 2 + 1] = vf * (float)(jj / WW);
    mconf[i] = valid ? conf : 0.0f;
    vout[i]  = vf;
}

extern "C" void kernel_launch(void* const* d_in, const int* in_sizes, int n_in,
                              void* d_out, int out_size, void* d_ws, size_t ws_size,
                              hipStream_t stream) {
    const float* f0 = (const float*)d_in[0];
    const float* f1 = (const float*)d_in[1];
    float* out = (float*)d_out;

    _Float16* A2 = (_Float16*)d_ws;                  // 6400x256 fp16
    _Float16* B2 = A2 + 6400 * 256;
    float* inv0   = (float*)(B2 + 6400 * 256);
    float* inv1   = inv0 + 6400;
    float* rowsum = inv1 + 6400;                     // then colsum (contiguous)
    float* colsum = rowsum + 6400;
    unsigned long long* rowbest = (unsigned long long*)(colsum + 6400);
    unsigned long long* colbest = rowbest + 6400;

    // zero rowsum/colsum (51,200 B) + rowbest/colbest (102,400 B), contiguous
    hipMemsetAsync(rowsum, 0, 153600, stream);

    knorm<<<50, 256, 0, stream>>>(f0, f1, inv0, inv1);
    ktrans<<<dim3(200, 8), 256, 0, stream>>>(f0, inv0, A2);
    ktrans<<<dim3(200, 8), 256, 0, stream>>>(f1, inv1, B2);
    kgemm1<<<dim3(50, 50), 256, 0, stream>>>(A2, B2, rowsum, colsum);
    kinv<<<50, 256, 0, stream>>>(rowsum);            // inverts rowsum AND colsum
    kgemm2<<<dim3(50, 50), 256, 0, stream>>>(A2, B2, rowsum, colsum,
                                             out, rowbest, colbest);
    kmatch<<<25, 256, 0, stream>>>(rowbest, colbest, out);
}